// Round 8
// baseline (713.918 us; speedup 1.0000x reference)
//
#include <hip/hip_runtime.h>
#include <hip/hip_bf16.h>
#include <cstdint>
#include <cstddef>

// out[8192,4096] = x @ W^T + bias + 2*((x@A^T)@B^T)
// R10: fold kernel DELETED (was ~240us). LoRA fused into the GEMM but OUTSIDE
//      the asm-scheduled main loop (R9's in-loop fusion overflowed the 256-reg
//      cap -> spill of in-flight asm ds_read dests -> NaN):
//        - prep = pure streaming cast (x,W -> bf16), ~288 MB.
//        - gemm PROLOGUE: per-wave xa = X_tile@A^T (plain loads + MFMA,
//          compiler-waited), parked in +8KB LDS; __syncthreads() drains all
//          counters so the R8 staging bookkeeping starts clean.
//        - R8 ring-4 main loop BYTE-IDENTICAL (passed @246us).
//        - EPILOGUE: 32 LoRA MFMAs (K=16 zero-padded), bias, store.

#define IN_F   4096
#define OUT_F  4096
#define MROWS  8192   // 4*2048
#define RLORA  16
#define LORA_SCALE 2.0f

// GEMM geometry
#define BM   256
#define BN   256
#define BKT  32               // K per LDS slot
#define NT   (IN_F / BKT)     // 128 slots

typedef __bf16 bf16x8 __attribute__((ext_vector_type(8)));
typedef float  f32x4  __attribute__((ext_vector_type(4)));
typedef int    i32x4  __attribute__((ext_vector_type(4)));

__device__ __forceinline__ unsigned short f2bf_rne(float f) {
    union { float f; unsigned u; } v; v.f = f;
    unsigned u = v.u;
    return (unsigned short)((u + 0x7FFFu + ((u >> 16) & 1u)) >> 16);
}

__device__ __forceinline__ void gl_lds16(const unsigned short* g, unsigned short* l) {
    __builtin_amdgcn_global_load_lds(
        (const __attribute__((address_space(1))) unsigned int*)g,
        (__attribute__((address_space(3))) unsigned int*)l,
        16, 0, 0);
}

__device__ __forceinline__ int cvtpk(float lo, float hi) {
    int r;
    asm volatile("v_cvt_pk_bf16_f32 %0, %1, %2" : "=v"(r) : "v"(lo), "v"(hi));
    return r;
}

// ---- prep: pure streaming cast, grid-stride --------------------------------

#define XF4   8388608u            // x float4 count
#define TOTF4 12582912u           // + W float4 count (4194304)
#define CAST_GRID 2048

__global__ void cast_xw(const float* __restrict__ x,
                        const float* __restrict__ W,
                        unsigned short* __restrict__ xb,
                        unsigned short* __restrict__ wbc) {
    const unsigned stride = CAST_GRID * 256;
    for (unsigned i = blockIdx.x * 256 + threadIdx.x; i < TOTF4; i += stride) {
        float4 v;
        if (i < XF4) v = ((const float4*)x)[i];
        else         v = ((const float4*)W)[i - XF4];
        ushort4 o;
        o.x = f2bf_rne(v.x); o.y = f2bf_rne(v.y);
        o.z = f2bf_rne(v.z); o.w = f2bf_rne(v.w);
        if (i < XF4) ((ushort4*)xb)[i] = o;
        else         ((ushort4*)wbc)[i - XF4] = o;
    }
}

// ---- GEMM: C = Xb @ Wbc^T + bias + xa @ (2B)^T  (R8 core + pro/epilogue) ---
//
// LDS chunk swizzle (chunk = 16 B): LDS chunk q of a slot holds global chunk
// (row=q>>2, kc=(q&3)^((row>>1)&3)); gl_lds writes linear, source pre-swizzled.
// R8 pipeline invariants unchanged: stage t during t-3; end-of-slot vmcnt(4)
// retires stage(p+2), leaves stage(p+3); lgkm(8) mid-slot; 1 barrier/slot.

__global__ __launch_bounds__(512, 2)
void gemm_bt_bias(const unsigned short* __restrict__ Xb,
                  const unsigned short* __restrict__ Wbc,
                  const float* __restrict__ bias,
                  const float* __restrict__ Asrc,
                  const float* __restrict__ Bsrc,
                  float* __restrict__ out) {
    // 4 ring slots x (A 16KB + B 16KB) = 128 KB, + xa_sh 8 KB = 136 KB
    __shared__ __align__(16) unsigned short smem[4 * 16384 + 4096];
    unsigned short* const xa_sh = smem + 4 * 16384;   // [256][16] bf16

    const int tid  = threadIdx.x;
    const int wave = tid >> 6;
    const int lane = tid & 63;
    const int quad = lane >> 4;
    const int r16  = lane & 15;
    const int wm   = wave >> 2;     // 0..1 (M half: 128 rows)
    const int wn   = wave & 3;      // 0..3 (N quarter: 64 cols)

    // XCD swizzle: XCD c owns N-tiles {2c,2c+1}; W panel 4 MB = its whole L2.
    const int bid = blockIdx.x;
    const int xcd = bid & 7;
    const int t   = bid >> 3;
    const int n0  = (xcd * 2 + (t & 1)) * BN;
    const int m0  = (t >> 1) * BM;

    // ---- xa prologue: xa_sh[256][16] = bf16( X_tile @ A^T ) ----------------
    // Wave owns 32 rows (wm*128 + wn*32 ..). Plain loads (compiler-waited),
    // 2 MFMA per 32-K step. __syncthreads() drains vm/lgkm afterwards.
    {
        const int R0 = m0 + wm * 128 + wn * 32;
        const unsigned short* xp = Xb + (size_t)(R0 + r16) * IN_F + quad * 8;
        const float*          ap = Asrc + (size_t)r16 * IN_F + quad * 8;
        f32x4 xa0 = {}, xa1 = {};
        #pragma unroll 4
        for (int s = 0; s < NT; ++s) {
            const i32x4 xv0 = *(const i32x4*)xp;
            const i32x4 xv1 = *(const i32x4*)(xp + 16 * IN_F);
            const f32x4 a0  = *(const f32x4*)ap;
            const f32x4 a1  = *(const f32x4*)(ap + 4);
            xp += BKT; ap += BKT;
            i32x4 abw;
            abw[0] = cvtpk(a0[0], a0[1]); abw[1] = cvtpk(a0[2], a0[3]);
            abw[2] = cvtpk(a1[0], a1[1]); abw[3] = cvtpk(a1[2], a1[3]);
            xa0 = __builtin_amdgcn_mfma_f32_16x16x32_bf16(
                __builtin_bit_cast(bf16x8, xv0), __builtin_bit_cast(bf16x8, abw), xa0, 0, 0, 0);
            xa1 = __builtin_amdgcn_mfma_f32_16x16x32_bf16(
                __builtin_bit_cast(bf16x8, xv1), __builtin_bit_cast(bf16x8, abw), xa1, 0, 0, 0);
        }
        const int rb = wm * 128 + wn * 32;
        #pragma unroll
        for (int i = 0; i < 4; ++i) {
            xa_sh[(rb +      quad * 4 + i) * 16 + r16] = f2bf_rne(xa0[i]);
            xa_sh[(rb + 16 + quad * 4 + i) * 16 + r16] = f2bf_rne(xa1[i]);
        }
        __syncthreads();
    }

    // ---- staging geometry (R8 verbatim) ------------------------------------
    const int q0  = wave * 128 + lane;
    const int q1  = q0 + 64;
    const int r0  = q0 >> 2, k0c = (q0 & 3) ^ ((r0 >> 1) & 3);
    const int r1  = q1 >> 2, k1c = (q1 & 3) ^ ((r1 >> 1) & 3);

    const unsigned short* gA0 = Xb  + (size_t)(m0 + r0) * IN_F + k0c * 8;
    const unsigned short* gA1 = Xb  + (size_t)(m0 + r1) * IN_F + k1c * 8;
    const unsigned short* gB0 = Wbc + (size_t)(n0 + r0) * IN_F + k0c * 8;
    const unsigned short* gB1 = Wbc + (size_t)(n0 + r1) * IN_F + k1c * 8;

    unsigned short* const lA0 = smem + wave * 1024;
    unsigned short* const lA1 = lA0 + 512;
    unsigned short* const lB0 = smem + 8192 + wave * 1024;
    unsigned short* const lB1 = lB0 + 512;

    const unsigned slot  = (unsigned)(quad ^ ((r16 >> 1) & 3));
    const unsigned aoff  = (unsigned)((wm * 128 + r16) * 64) + slot * 16;
    const unsigned boff  = 16384u + (unsigned)((wn * 64 + r16) * 64) + slot * 16;
    const unsigned sbase = (unsigned)(size_t)
        ((__attribute__((address_space(3))) unsigned short*)smem);

    f32x4 acc[8][4] = {};
    i32x4 aE[8], bE[4], aO[8], bO[4];

#define STAGE(TILE) {                                                    \
    const unsigned off = (unsigned)(((TILE) & 3) << 14);                 \
    gl_lds16(gA0, lA0 + off); gl_lds16(gA1, lA1 + off);                  \
    gl_lds16(gB0, lB0 + off); gl_lds16(gB1, lB1 + off);                  \
    gA0 += BKT; gA1 += BKT; gB0 += BKT; gB1 += BKT; }

#define RD_LO(AV, BV, S) {                                               \
    const unsigned bufb_ = sbase + ((unsigned)((S) & 3) << 15);          \
    const unsigned ab_ = bufb_ + aoff, bb_ = bufb_ + boff;               \
    asm volatile("ds_read_b128 %0, %1"             : "=v"(BV[0]) : "v"(bb_)); \
    asm volatile("ds_read_b128 %0, %1 offset:1024" : "=v"(BV[1]) : "v"(bb_)); \
    asm volatile("ds_read_b128 %0, %1 offset:2048" : "=v"(BV[2]) : "v"(bb_)); \
    asm volatile("ds_read_b128 %0, %1 offset:3072" : "=v"(BV[3]) : "v"(bb_)); \
    asm volatile("ds_read_b128 %0, %1"             : "=v"(AV[0]) : "v"(ab_)); \
    asm volatile("ds_read_b128 %0, %1 offset:1024" : "=v"(AV[1]) : "v"(ab_)); \
    asm volatile("ds_read_b128 %0, %1 offset:2048" : "=v"(AV[2]) : "v"(ab_)); \
    asm volatile("ds_read_b128 %0, %1 offset:3072" : "=v"(AV[3]) : "v"(ab_)); }

#define RD_HI(AV, S) {                                                   \
    const unsigned bufb_ = sbase + ((unsigned)((S) & 3) << 15);          \
    const unsigned ab_ = bufb_ + aoff;                                   \
    asm volatile("ds_read_b128 %0, %1 offset:4096" : "=v"(AV[4]) : "v"(ab_)); \
    asm volatile("ds_read_b128 %0, %1 offset:5120" : "=v"(AV[5]) : "v"(ab_)); \
    asm volatile("ds_read_b128 %0, %1 offset:6144" : "=v"(AV[6]) : "v"(ab_)); \
    asm volatile("ds_read_b128 %0, %1 offset:7168" : "=v"(AV[7]) : "v"(ab_)); }

#define CLUSTER(AV, BV, MLO, MHI) {                                      \
    _Pragma("unroll")                                                    \
    for (int mi = MLO; mi < MHI; ++mi) {                                 \
        const bf16x8 a_ = __builtin_bit_cast(bf16x8, AV[mi]);            \
        _Pragma("unroll")                                                \
        for (int nj = 0; nj < 4; ++nj)                                   \
            acc[mi][nj] = __builtin_amdgcn_mfma_f32_16x16x32_bf16(       \
                a_, __builtin_bit_cast(bf16x8, BV[nj]), acc[mi][nj], 0, 0, 0); \
    } }

    // ---- prologue ----------------------------------------------------------
    STAGE(0) STAGE(1) STAGE(2)
    asm volatile("s_waitcnt vmcnt(4)" ::: "memory");   // slots 0 AND 1 resident
    __builtin_amdgcn_s_barrier();
    RD_LO(aE, bE, 0)
    asm volatile("s_waitcnt lgkmcnt(0)" ::: "memory");
    __builtin_amdgcn_sched_barrier(0);

    // ---- main loop: pairs of slots (0..125) --------------------------------
    for (int p = 0; p < NT - 2; p += 2) {
        // ---- even slot s = p (set E), prefetch O for s+1 ----
        RD_HI(aE, p)
        RD_LO(aO, bO, p + 1)
        STAGE(p + 3)                        // p+3 <= 127 in loop
        __builtin_amdgcn_sched_barrier(0);
        __builtin_amdgcn_s_setprio(1);
        CLUSTER(aE, bE, 0, 4)
        asm volatile("s_waitcnt lgkmcnt(8)" ::: "memory");   // aE[4..7] done
        __builtin_amdgcn_sched_barrier(0);
        CLUSTER(aE, bE, 4, 8)
        __builtin_amdgcn_s_setprio(0);
        __builtin_amdgcn_sched_barrier(0);
        asm volatile("s_waitcnt lgkmcnt(0)" ::: "memory");   // O prefetch done
        __builtin_amdgcn_sched_barrier(0);
        asm volatile("s_waitcnt vmcnt(4)" ::: "memory");     // p+1,p+2 resident
        __builtin_amdgcn_s_barrier();

        // ---- odd slot s = p+1 (set O), prefetch E for s+2 ----
        RD_HI(aO, p + 1)
        RD_LO(aE, bE, p + 2)
        if (p + 4 < NT) STAGE(p + 4)
        __builtin_amdgcn_sched_barrier(0);
        __builtin_amdgcn_s_setprio(1);
        CLUSTER(aO, bO, 0, 4)
        asm volatile("s_waitcnt lgkmcnt(8)" ::: "memory");   // aO[4..7] done
        __builtin_amdgcn_sched_barrier(0);
        CLUSTER(aO, bO, 4, 8)
        __builtin_amdgcn_s_setprio(0);
        __builtin_amdgcn_sched_barrier(0);
        asm volatile("s_waitcnt lgkmcnt(0)" ::: "memory");   // E prefetch done
        __builtin_amdgcn_sched_barrier(0);
        if (p + 4 < NT) { asm volatile("s_waitcnt vmcnt(4)" ::: "memory"); }
        else            { asm volatile("s_waitcnt vmcnt(0)" ::: "memory"); }
        __builtin_amdgcn_s_barrier();
    }

    // ---- peeled slot 126 (set E), prefetch O for 127; no stage -------------
    RD_HI(aE, NT - 2)
    RD_LO(aO, bO, NT - 1)
    __builtin_amdgcn_sched_barrier(0);
    __builtin_amdgcn_s_setprio(1);
    CLUSTER(aE, bE, 0, 4)
    asm volatile("s_waitcnt lgkmcnt(8)" ::: "memory");
    __builtin_amdgcn_sched_barrier(0);
    CLUSTER(aE, bE, 4, 8)
    __builtin_amdgcn_s_setprio(0);
    __builtin_amdgcn_sched_barrier(0);
    asm volatile("s_waitcnt lgkmcnt(0)" ::: "memory");
    __builtin_amdgcn_sched_barrier(0);
    asm volatile("s_waitcnt vmcnt(0)" ::: "memory");
    __builtin_amdgcn_s_barrier();

    // ---- peeled slot 127 (set O); no prefetch ------------------------------
    RD_HI(aO, NT - 1)
    __builtin_amdgcn_sched_barrier(0);
    __builtin_amdgcn_s_setprio(1);
    CLUSTER(aO, bO, 0, 4)
    asm volatile("s_waitcnt lgkmcnt(0)" ::: "memory");   // only 4 outstanding
    __builtin_amdgcn_sched_barrier(0);
    CLUSTER(aO, bO, 4, 8)
    __builtin_amdgcn_s_setprio(0);

#undef STAGE
#undef RD_LO
#undef RD_HI
#undef CLUSTER

    // ---- LoRA epilogue: acc += xa @ (2B)^T  (K=16 zero-padded to 32) -------
    {
        i32x4 aL[8], bL[4];
        #pragma unroll
        for (int mi = 0; mi < 8; ++mi) {
            i32x4 v = {};
            if (quad < 2)
                v = *(const i32x4*)(xa_sh + (wm * 128 + mi * 16 + r16) * 16 + quad * 8);
            aL[mi] = v;
        }
        #pragma unroll
        for (int nj = 0; nj < 4; ++nj) {
            f32x4 b0 = {}, b1 = {};
            if (quad < 2) {
                const float* bp = Bsrc + (size_t)(n0 + wn * 64 + nj * 16 + r16) * RLORA + quad * 8;
                b0 = *(const f32x4*)bp;
                b1 = *(const f32x4*)(bp + 4);
            }
            i32x4 w;
            w[0] = cvtpk(LORA_SCALE * b0[0], LORA_SCALE * b0[1]);
            w[1] = cvtpk(LORA_SCALE * b0[2], LORA_SCALE * b0[3]);
            w[2] = cvtpk(LORA_SCALE * b1[0], LORA_SCALE * b1[1]);
            w[3] = cvtpk(LORA_SCALE * b1[2], LORA_SCALE * b1[3]);
            bL[nj] = w;
        }
        #pragma unroll
        for (int mi = 0; mi < 8; ++mi) {
            const bf16x8 a_ = __builtin_bit_cast(bf16x8, aL[mi]);
            #pragma unroll
            for (int nj = 0; nj < 4; ++nj)
                acc[mi][nj] = __builtin_amdgcn_mfma_f32_16x16x32_bf16(
                    a_, __builtin_bit_cast(bf16x8, bL[nj]), acc[mi][nj], 0, 0, 0);
        }
    }

    // ---- epilogue: C = acc + bias ------------------------------------------
    float bv[4];
    #pragma unroll
    for (int nj = 0; nj < 4; ++nj)
        bv[nj] = bias[n0 + wn * 64 + nj * 16 + r16];

    #pragma unroll
    for (int mi = 0; mi < 8; ++mi) {
        #pragma unroll
        for (int i = 0; i < 4; ++i) {
            const int mg = m0 + wm * 128 + mi * 16 + quad * 4 + i;
            float* orow = out + (size_t)mg * OUT_F + (n0 + wn * 64 + r16);
            #pragma unroll
            for (int nj = 0; nj < 4; ++nj)
                orow[nj * 16] = acc[mi][nj][i] + bv[nj];
        }
    }
}

// ---- launch ----------------------------------------------------------------

extern "C" void kernel_launch(void* const* d_in, const int* in_sizes, int n_in,
                              void* d_out, int out_size, void* d_ws, size_t ws_size,
                              hipStream_t stream) {
    const float* x    = (const float*)d_in[0];
    const float* W    = (const float*)d_in[1];
    const float* bias = (const float*)d_in[2];
    const float* A    = (const float*)d_in[3];
    const float* B    = (const float*)d_in[4];
    float* out = (float*)d_out;

    unsigned short* xb  = (unsigned short*)d_ws;             // 64 MB bf16 x
    unsigned short* wbc = xb + (size_t)MROWS * IN_F;         // 32 MB bf16 W

    cast_xw<<<CAST_GRID, 256, 0, stream>>>(x, W, xb, wbc);
    gemm_bt_bias<<<(MROWS / BM) * (OUT_F / BN), 512, 0, stream>>>(
        xb, wbc, bias, A, B, out);
}

// Round 9
// 608.943 us; speedup vs baseline: 1.1724x; 1.1724x over previous
//
#include <hip/hip_runtime.h>
#include <hip/hip_bf16.h>
#include <cstdint>
#include <cstddef>

// out[8192,4096] = x @ W^T + bias + 2*((x@A^T)@B^T)
// R11: fold kernel DELETED. Decomposition:
//   cast_xw : pure streaming cast x,W -> bf16 (~26us)
//   xa_k    : xa[8192][16] = x @ A^T via one 16x16x32 MFMA chain per wave;
//             reads X bf16 EXACTLY ONCE (R10's per-block re-read was the bug)
//   gemm    : R8 ring-4 main loop BYTE-IDENTICAL (best passing, 246us)
//             + R10's proven LoRA epilogue (xa from __device__ global)
// All scratch in __device__ globals; d_ws unused (no ws_size risk).

#define IN_F   4096
#define OUT_F  4096
#define MROWS  8192   // 4*2048
#define RLORA  16
#define LORA_SCALE 2.0f

// GEMM geometry
#define BM   256
#define BN   256
#define BKT  32               // K per LDS slot
#define NT   (IN_F / BKT)     // 128 slots

typedef __bf16 bf16x8 __attribute__((ext_vector_type(8)));
typedef float  f32x4  __attribute__((ext_vector_type(4)));
typedef int    i32x4  __attribute__((ext_vector_type(4)));

__device__ __align__(16) unsigned short g_xb[(size_t)MROWS * IN_F];   // 64 MB
__device__ __align__(16) unsigned short g_wb[(size_t)OUT_F * IN_F];   // 32 MB
__device__ __align__(16) unsigned short g_xa[MROWS * RLORA];          // 256 KB

__device__ __forceinline__ unsigned short f2bf_rne(float f) {
    union { float f; unsigned u; } v; v.f = f;
    unsigned u = v.u;
    return (unsigned short)((u + 0x7FFFu + ((u >> 16) & 1u)) >> 16);
}

__device__ __forceinline__ void gl_lds16(const unsigned short* g, unsigned short* l) {
    __builtin_amdgcn_global_load_lds(
        (const __attribute__((address_space(1))) unsigned int*)g,
        (__attribute__((address_space(3))) unsigned int*)l,
        16, 0, 0);
}

__device__ __forceinline__ int cvtpk(float lo, float hi) {
    int r;
    asm volatile("v_cvt_pk_bf16_f32 %0, %1, %2" : "=v"(r) : "v"(lo), "v"(hi));
    return r;
}

// ---- prep 1: pure streaming cast, grid-stride ------------------------------

#define XF4   8388608u            // x float4 count
#define TOTF4 12582912u           // + W float4 count (4194304)
#define CAST_GRID 2048

__global__ void cast_xw(const float* __restrict__ x,
                        const float* __restrict__ W) {
    const unsigned stride = CAST_GRID * 256;
    for (unsigned i = blockIdx.x * 256 + threadIdx.x; i < TOTF4; i += stride) {
        float4 v;
        if (i < XF4) v = ((const float4*)x)[i];
        else         v = ((const float4*)W)[i - XF4];
        ushort4 o;
        o.x = f2bf_rne(v.x); o.y = f2bf_rne(v.y);
        o.z = f2bf_rne(v.z); o.w = f2bf_rne(v.w);
        if (i < XF4) ((ushort4*)g_xb)[i] = o;
        else         ((ushort4*)g_wb)[i - XF4] = o;
    }
}

// ---- prep 2: xa = x @ A^T  (one MFMA chain per wave, X read once) ----------
// Wave handles 16 X-rows. A-frag: X[row=r16][k=quad*8..], B-frag:
// A[rr=r16][k=quad*8..] (f32->cvt_pk). C: row=quad*4+i, col=r16 (verified
// 16x16x32 layouts, same as the gemm's fragment conventions).

__global__ void xa_k(const float* __restrict__ Asrc) {
    const int tid  = threadIdx.x;
    const int wave = tid >> 6;
    const int lane = tid & 63;
    const int quad = lane >> 4;
    const int r16  = lane & 15;
    const int row0 = blockIdx.x * 64 + wave * 16;

    const unsigned short* xp = g_xb + (size_t)(row0 + r16) * IN_F + quad * 8;
    const float*          ap = Asrc + (size_t)r16 * IN_F + quad * 8;

    f32x4 acc = {};
    #pragma unroll 8
    for (int s = 0; s < NT; ++s) {
        const i32x4 xv = *(const i32x4*)xp;
        const f32x4 a0 = *(const f32x4*)ap;
        const f32x4 a1 = *(const f32x4*)(ap + 4);
        xp += BKT; ap += BKT;
        i32x4 abw;
        abw[0] = cvtpk(a0[0], a0[1]); abw[1] = cvtpk(a0[2], a0[3]);
        abw[2] = cvtpk(a1[0], a1[1]); abw[3] = cvtpk(a1[2], a1[3]);
        acc = __builtin_amdgcn_mfma_f32_16x16x32_bf16(
            __builtin_bit_cast(bf16x8, xv), __builtin_bit_cast(bf16x8, abw), acc, 0, 0, 0);
    }
    #pragma unroll
    for (int i = 0; i < 4; ++i)
        g_xa[(size_t)(row0 + quad * 4 + i) * RLORA + r16] = f2bf_rne(acc[i]);
}

// ---- GEMM: C = Xb @ Wb^T + bias + xa @ (2B)^T  (R8 core + LoRA epilogue) ---
//
// LDS chunk swizzle (chunk = 16 B): LDS chunk q of a slot holds global chunk
// (row=q>>2, kc=(q&3)^((row>>1)&3)); gl_lds writes linear, source pre-swizzled.
// R8 invariants: stage t during t-3; end-of-slot vmcnt(4) retires stage(p+2);
// lgkm(8) mid-slot; lgkm(0) before the barrier (ALSO makes the loop-carried
// asm ds_read dests compiler-safe — do not remove); 1 barrier/slot.

__global__ __launch_bounds__(512, 2)
void gemm_bt_bias(const float* __restrict__ bias,
                  const float* __restrict__ Bsrc,
                  float* __restrict__ out) {
    __shared__ __align__(16) unsigned short smem[4 * 16384];  // 4 x (A 16KB + B 16KB)

    const int tid  = threadIdx.x;
    const int wave = tid >> 6;
    const int lane = tid & 63;
    const int quad = lane >> 4;
    const int r16  = lane & 15;
    const int wm   = wave >> 2;     // 0..1 (M half: 128 rows)
    const int wn   = wave & 3;      // 0..3 (N quarter: 64 cols)

    // XCD swizzle: XCD c owns N-tiles {2c,2c+1}; W panel 4 MB = its whole L2.
    const int bid = blockIdx.x;
    const int xcd = bid & 7;
    const int t   = bid >> 3;
    const int n0  = (xcd * 2 + (t & 1)) * BN;
    const int m0  = (t >> 1) * BM;

    // staging geometry: thread owns LDS chunks q0, q1 of A and of B per slot
    const int q0  = wave * 128 + lane;
    const int q1  = q0 + 64;
    const int r0  = q0 >> 2, k0c = (q0 & 3) ^ ((r0 >> 1) & 3);
    const int r1  = q1 >> 2, k1c = (q1 & 3) ^ ((r1 >> 1) & 3);

    const unsigned short* gA0 = g_xb + (size_t)(m0 + r0) * IN_F + k0c * 8;
    const unsigned short* gA1 = g_xb + (size_t)(m0 + r1) * IN_F + k1c * 8;
    const unsigned short* gB0 = g_wb + (size_t)(n0 + r0) * IN_F + k0c * 8;
    const unsigned short* gB1 = g_wb + (size_t)(n0 + r1) * IN_F + k1c * 8;

    unsigned short* const lA0 = smem + wave * 1024;
    unsigned short* const lA1 = lA0 + 512;
    unsigned short* const lB0 = smem + 8192 + wave * 1024;
    unsigned short* const lB1 = lB0 + 512;

    const unsigned slot  = (unsigned)(quad ^ ((r16 >> 1) & 3));
    const unsigned aoff  = (unsigned)((wm * 128 + r16) * 64) + slot * 16;
    const unsigned boff  = 16384u + (unsigned)((wn * 64 + r16) * 64) + slot * 16;
    const unsigned sbase = (unsigned)(size_t)
        ((__attribute__((address_space(3))) unsigned short*)smem);

    f32x4 acc[8][4] = {};
    i32x4 aE[8], bE[4], aO[8], bO[4];

#define STAGE(TILE) {                                                    \
    const unsigned off = (unsigned)(((TILE) & 3) << 14);                 \
    gl_lds16(gA0, lA0 + off); gl_lds16(gA1, lA1 + off);                  \
    gl_lds16(gB0, lB0 + off); gl_lds16(gB1, lB1 + off);                  \
    gA0 += BKT; gA1 += BKT; gB0 += BKT; gB1 += BKT; }

#define RD_LO(AV, BV, S) {                                               \
    const unsigned bufb_ = sbase + ((unsigned)((S) & 3) << 15);          \
    const unsigned ab_ = bufb_ + aoff, bb_ = bufb_ + boff;               \
    asm volatile("ds_read_b128 %0, %1"             : "=v"(BV[0]) : "v"(bb_)); \
    asm volatile("ds_read_b128 %0, %1 offset:1024" : "=v"(BV[1]) : "v"(bb_)); \
    asm volatile("ds_read_b128 %0, %1 offset:2048" : "=v"(BV[2]) : "v"(bb_)); \
    asm volatile("ds_read_b128 %0, %1 offset:3072" : "=v"(BV[3]) : "v"(bb_)); \
    asm volatile("ds_read_b128 %0, %1"             : "=v"(AV[0]) : "v"(ab_)); \
    asm volatile("ds_read_b128 %0, %1 offset:1024" : "=v"(AV[1]) : "v"(ab_)); \
    asm volatile("ds_read_b128 %0, %1 offset:2048" : "=v"(AV[2]) : "v"(ab_)); \
    asm volatile("ds_read_b128 %0, %1 offset:3072" : "=v"(AV[3]) : "v"(ab_)); }

#define RD_HI(AV, S) {                                                   \
    const unsigned bufb_ = sbase + ((unsigned)((S) & 3) << 15);          \
    const unsigned ab_ = bufb_ + aoff;                                   \
    asm volatile("ds_read_b128 %0, %1 offset:4096" : "=v"(AV[4]) : "v"(ab_)); \
    asm volatile("ds_read_b128 %0, %1 offset:5120" : "=v"(AV[5]) : "v"(ab_)); \
    asm volatile("ds_read_b128 %0, %1 offset:6144" : "=v"(AV[6]) : "v"(ab_)); \
    asm volatile("ds_read_b128 %0, %1 offset:7168" : "=v"(AV[7]) : "v"(ab_)); }

#define CLUSTER(AV, BV, MLO, MHI) {                                      \
    _Pragma("unroll")                                                    \
    for (int mi = MLO; mi < MHI; ++mi) {                                 \
        const bf16x8 a_ = __builtin_bit_cast(bf16x8, AV[mi]);            \
        _Pragma("unroll")                                                \
        for (int nj = 0; nj < 4; ++nj)                                   \
            acc[mi][nj] = __builtin_amdgcn_mfma_f32_16x16x32_bf16(       \
                a_, __builtin_bit_cast(bf16x8, BV[nj]), acc[mi][nj], 0, 0, 0); \
    } }

    // ---- prologue ----------------------------------------------------------
    STAGE(0) STAGE(1) STAGE(2)
    asm volatile("s_waitcnt vmcnt(4)" ::: "memory");   // slots 0 AND 1 resident
    __builtin_amdgcn_s_barrier();
    RD_LO(aE, bE, 0)
    asm volatile("s_waitcnt lgkmcnt(0)" ::: "memory");
    __builtin_amdgcn_sched_barrier(0);

    // ---- main loop: pairs of slots (0..125) --------------------------------
    for (int p = 0; p < NT - 2; p += 2) {
        // ---- even slot s = p (set E), prefetch O for s+1 ----
        RD_HI(aE, p)
        RD_LO(aO, bO, p + 1)
        STAGE(p + 3)                        // p+3 <= 127 in loop
        __builtin_amdgcn_sched_barrier(0);
        __builtin_amdgcn_s_setprio(1);
        CLUSTER(aE, bE, 0, 4)
        asm volatile("s_waitcnt lgkmcnt(8)" ::: "memory");   // aE[4..7] done
        __builtin_amdgcn_sched_barrier(0);
        CLUSTER(aE, bE, 4, 8)
        __builtin_amdgcn_s_setprio(0);
        __builtin_amdgcn_sched_barrier(0);
        asm volatile("s_waitcnt lgkmcnt(0)" ::: "memory");   // O prefetch done
        __builtin_amdgcn_sched_barrier(0);
        asm volatile("s_waitcnt vmcnt(4)" ::: "memory");     // p+1,p+2 resident
        __builtin_amdgcn_s_barrier();

        // ---- odd slot s = p+1 (set O), prefetch E for s+2 ----
        RD_HI(aO, p + 1)
        RD_LO(aE, bE, p + 2)
        if (p + 4 < NT) STAGE(p + 4)
        __builtin_amdgcn_sched_barrier(0);
        __builtin_amdgcn_s_setprio(1);
        CLUSTER(aO, bO, 0, 4)
        asm volatile("s_waitcnt lgkmcnt(8)" ::: "memory");   // aO[4..7] done
        __builtin_amdgcn_sched_barrier(0);
        CLUSTER(aO, bO, 4, 8)
        __builtin_amdgcn_s_setprio(0);
        __builtin_amdgcn_sched_barrier(0);
        asm volatile("s_waitcnt lgkmcnt(0)" ::: "memory");   // E prefetch done
        __builtin_amdgcn_sched_barrier(0);
        if (p + 4 < NT) { asm volatile("s_waitcnt vmcnt(4)" ::: "memory"); }
        else            { asm volatile("s_waitcnt vmcnt(0)" ::: "memory"); }
        __builtin_amdgcn_s_barrier();
    }

    // ---- peeled slot 126 (set E), prefetch O for 127; no stage -------------
    RD_HI(aE, NT - 2)
    RD_LO(aO, bO, NT - 1)
    __builtin_amdgcn_sched_barrier(0);
    __builtin_amdgcn_s_setprio(1);
    CLUSTER(aE, bE, 0, 4)
    asm volatile("s_waitcnt lgkmcnt(8)" ::: "memory");
    __builtin_amdgcn_sched_barrier(0);
    CLUSTER(aE, bE, 4, 8)
    __builtin_amdgcn_s_setprio(0);
    __builtin_amdgcn_sched_barrier(0);
    asm volatile("s_waitcnt lgkmcnt(0)" ::: "memory");
    __builtin_amdgcn_sched_barrier(0);
    asm volatile("s_waitcnt vmcnt(0)" ::: "memory");
    __builtin_amdgcn_s_barrier();

    // ---- peeled slot 127 (set O); no prefetch ------------------------------
    RD_HI(aO, NT - 1)
    __builtin_amdgcn_sched_barrier(0);
    __builtin_amdgcn_s_setprio(1);
    CLUSTER(aO, bO, 0, 4)
    asm volatile("s_waitcnt lgkmcnt(0)" ::: "memory");   // only 4 outstanding
    __builtin_amdgcn_sched_barrier(0);
    CLUSTER(aO, bO, 4, 8)
    __builtin_amdgcn_s_setprio(0);

#undef STAGE
#undef RD_LO
#undef RD_HI
#undef CLUSTER

    // ---- LoRA epilogue: acc += xa @ (2B)^T  (K=16 zero-padded to 32) -------
    {
        i32x4 aL[8], bL[4];
        #pragma unroll
        for (int mi = 0; mi < 8; ++mi) {
            i32x4 v = {};
            if (quad < 2)
                v = *(const i32x4*)(g_xa +
                        (size_t)(m0 + wm * 128 + mi * 16 + r16) * RLORA + quad * 8);
            aL[mi] = v;
        }
        #pragma unroll
        for (int nj = 0; nj < 4; ++nj) {
            f32x4 b0 = {}, b1 = {};
            if (quad < 2) {
                const float* bp = Bsrc + (size_t)(n0 + wn * 64 + nj * 16 + r16) * RLORA + quad * 8;
                b0 = *(const f32x4*)bp;
                b1 = *(const f32x4*)(bp + 4);
            }
            i32x4 w;
            w[0] = cvtpk(LORA_SCALE * b0[0], LORA_SCALE * b0[1]);
            w[1] = cvtpk(LORA_SCALE * b0[2], LORA_SCALE * b0[3]);
            w[2] = cvtpk(LORA_SCALE * b1[0], LORA_SCALE * b1[1]);
            w[3] = cvtpk(LORA_SCALE * b1[2], LORA_SCALE * b1[3]);
            bL[nj] = w;
        }
        #pragma unroll
        for (int mi = 0; mi < 8; ++mi) {
            const bf16x8 a_ = __builtin_bit_cast(bf16x8, aL[mi]);
            #pragma unroll
            for (int nj = 0; nj < 4; ++nj)
                acc[mi][nj] = __builtin_amdgcn_mfma_f32_16x16x32_bf16(
                    a_, __builtin_bit_cast(bf16x8, bL[nj]), acc[mi][nj], 0, 0, 0);
        }
    }

    // ---- epilogue: C = acc + bias ------------------------------------------
    float bv[4];
    #pragma unroll
    for (int nj = 0; nj < 4; ++nj)
        bv[nj] = bias[n0 + wn * 64 + nj * 16 + r16];

    #pragma unroll
    for (int mi = 0; mi < 8; ++mi) {
        #pragma unroll
        for (int i = 0; i < 4; ++i) {
            const int mg = m0 + wm * 128 + mi * 16 + quad * 4 + i;
            float* orow = out + (size_t)mg * OUT_F + (n0 + wn * 64 + r16);
            #pragma unroll
            for (int nj = 0; nj < 4; ++nj)
                orow[nj * 16] = acc[mi][nj][i] + bv[nj];
        }
    }
}

// ---- launch ----------------------------------------------------------------

extern "C" void kernel_launch(void* const* d_in, const int* in_sizes, int n_in,
                              void* d_out, int out_size, void* d_ws, size_t ws_size,
                              hipStream_t stream) {
    const float* x    = (const float*)d_in[0];
    const float* W    = (const float*)d_in[1];
    const float* bias = (const float*)d_in[2];
    const float* A    = (const float*)d_in[3];
    const float* B    = (const float*)d_in[4];
    float* out = (float*)d_out;
    (void)d_ws; (void)ws_size;

    cast_xw<<<CAST_GRID, 256, 0, stream>>>(x, W);
    xa_k<<<MROWS / 64, 256, 0, stream>>>(A);
    gemm_bt_bias<<<(MROWS / BM) * (OUT_F / BN), 512, 0, stream>>>(bias, B, out);
}